// Round 1
// 530.166 us; speedup vs baseline: 1.0480x; 1.0480x over previous
//
#include <hip/hip_runtime.h>
#include <hip/hip_bf16.h>
#include <stdint.h>

#define IN_CH 64
#define OUT_CH 128

typedef __bf16 bf16x8 __attribute__((ext_vector_type(8)));
typedef float  f32x4  __attribute__((ext_vector_type(4)));

__device__ inline unsigned short f2bf(float f) {
    unsigned u = __float_as_uint(f);
    unsigned r = (u + 0x7fffu + ((u >> 16) & 1u)) >> 16;
    return (unsigned short)r;
}

// ---------- fast path ----------

// Fill inv[n_out*9] with the zero-row index; zero sums[256].
__global__ void __launch_bounds__(256) init_inv_kernel(
    int* __restrict__ inv, int total, int zero_row, float* __restrict__ sums) {
    int i = blockIdx.x * 256 + threadIdx.x;
    if (i < total) inv[i] = zero_row;
    if (blockIdx.x == 0) sums[threadIdx.x] = 0.f;
}

// feats fp32 -> bf16 (RNE). n4 = N_in*IN_CH/4. Appends one zero row at N_in.
__global__ void __launch_bounds__(256) feats_bf16_kernel(
    const float4* __restrict__ f4, ushort* __restrict__ fb, int n4) {
    int i = blockIdx.x * 256 + threadIdx.x;
    if (i >= n4 + 16) return;
    ushort4 o;
    if (i < n4) {
        float4 v = f4[i];
        o.x = f2bf(v.x); o.y = f2bf(v.y); o.z = f2bf(v.z); o.w = f2bf(v.w);
    } else {
        o.x = 0; o.y = 0; o.z = 0; o.w = 0;   // zero row for absent entries
    }
    ((ushort4*)fb)[i] = o;
}

// Wbt[k][c][i] = bf16(W[k][i][c]); [9][128][64]
__global__ void __launch_bounds__(256) wbt_kernel(
    const float* __restrict__ W, ushort* __restrict__ wbt) {
    int idx = blockIdx.x * 256 + threadIdx.x;
    if (idx >= 9 * OUT_CH * IN_CH) return;
    int i = idx & (IN_CH - 1);
    int c = (idx >> 6) & (OUT_CH - 1);
    int k = idx >> 13;
    wbt[idx] = f2bf(W[((size_t)k * IN_CH + i) * OUT_CH + c]);
}

// Inverse rulebook, atomic-free: for fixed k the in->out map of a strided
// conv is injective, so inv[out*9+k] has exactly one writer.
__global__ void __launch_bounds__(256) build_inv_kernel(
    const int* __restrict__ in_idx,
    const int* __restrict__ out_idx,
    const int* __restrict__ mask,
    int* __restrict__ inv,
    int R)
{
    int r = blockIdx.x * 256 + threadIdx.x;
    if (r >= R) return;
    int k = blockIdx.y;
    size_t e = (size_t)k * R + r;
    if (!mask[e]) return;
    inv[(size_t)out_idx[e] * 9 + k] = in_idx[e];
}

// Fused: out[r] = sum_k Wbt[k]^T . fb[inv[r][k]]  (absent -> zero row), plus
// fused BN-stat partials. Wave = 32 output rows x 128 channels (two 16-row
// MFMA groups sharing the B-fragments); block = 4 waves = 128 rows.
// Per k: Wbt[k] is 16 KB -> L1-resident; A rows gathered from L3-resident fb.
__global__ void __launch_bounds__(256, 2) fused_out_kernel(
    const ushort* __restrict__ fb,    // [N_in+1][64] bf16 (last row zeros)
    const ushort* __restrict__ wbt,   // [9][128][64] bf16
    const int* __restrict__ inv,      // [n_out][9]
    float* __restrict__ out,          // [n_out][128] fp32
    float* __restrict__ sums,         // [256]
    int n_out, int zero_row)
{
    const int lane = threadIdx.x & 63;
    const int w = threadIdx.x >> 6;
    const int col = lane & 15;
    const int quad = lane >> 4;
    const int base = blockIdx.x * 128 + w * 32;

    // Per-lane inverse lists for its two A-rows (fully unrolled -> registers).
    int ivA[9], ivB[9];
    {
        int rA = base + col;
        int rB = rA + 16;
        const int* __restrict__ pA = inv + (size_t)rA * 9;
        const int* __restrict__ pB = inv + (size_t)rB * 9;
        bool okA = rA < n_out;
        bool okB = rB < n_out;
#pragma unroll
        for (int k = 0; k < 9; ++k) ivA[k] = okA ? pA[k] : zero_row;
#pragma unroll
        for (int k = 0; k < 9; ++k) ivB[k] = okB ? pB[k] : zero_row;
    }

    f32x4 accA[8], accB[8];
#pragma unroll
    for (int g = 0; g < 8; ++g) {
        accA[g] = (f32x4){0.f, 0.f, 0.f, 0.f};
        accB[g] = (f32x4){0.f, 0.f, 0.f, 0.f};
    }

#pragma unroll
    for (int k = 0; k < 9; ++k) {
        const ushort* __restrict__ wk = wbt + (size_t)k * (OUT_CH * IN_CH);
        const ushort* __restrict__ fA = fb + (size_t)ivA[k] * IN_CH + quad * 8;
        const ushort* __restrict__ fBv = fb + (size_t)ivB[k] * IN_CH + quad * 8;
        bf16x8 A0 = *(const bf16x8*)fA;
        bf16x8 A1 = *(const bf16x8*)(fA + 32);
        bf16x8 C0 = *(const bf16x8*)fBv;
        bf16x8 C1 = *(const bf16x8*)(fBv + 32);
#pragma unroll
        for (int g = 0; g < 8; ++g) {
            const ushort* __restrict__ p = wk + (size_t)(g * 16 + col) * IN_CH + quad * 8;
            bf16x8 W0 = *(const bf16x8*)p;
            bf16x8 W1 = *(const bf16x8*)(p + 32);
            accA[g] = __builtin_amdgcn_mfma_f32_16x16x32_bf16(A0, W0, accA[g], 0, 0, 0);
            accA[g] = __builtin_amdgcn_mfma_f32_16x16x32_bf16(A1, W1, accA[g], 0, 0, 0);
            accB[g] = __builtin_amdgcn_mfma_f32_16x16x32_bf16(C0, W0, accB[g], 0, 0, 0);
            accB[g] = __builtin_amdgcn_mfma_f32_16x16x32_bf16(C1, W1, accB[g], 0, 0, 0);
        }
    }

    // Epilogue: store rows + BN stat partials (OOB rows computed zeros, so
    // they contribute nothing to the stats and are simply not stored).
    float s[8], q[8];
#pragma unroll
    for (int g = 0; g < 8; ++g) { s[g] = 0.f; q[g] = 0.f; }

#pragma unroll
    for (int r = 0; r < 4; ++r) {
        int rowA = base + quad * 4 + r;
        int rowB = rowA + 16;
#pragma unroll
        for (int g = 0; g < 8; ++g) {
            float vA = accA[g][r], vB = accB[g][r];
            s[g] += vA + vB;
            q[g] += vA * vA + vB * vB;
        }
        if (rowA < n_out) {
            float* __restrict__ rp = out + (size_t)rowA * OUT_CH + col;
#pragma unroll
            for (int g = 0; g < 8; ++g) rp[g * 16] = accA[g][r];
        }
        if (rowB < n_out) {
            float* __restrict__ rp = out + (size_t)rowB * OUT_CH + col;
#pragma unroll
            for (int g = 0; g < 8; ++g) rp[g * 16] = accB[g][r];
        }
    }

    // Cross-quad reduce (lanes with equal col hold the same channel set).
#pragma unroll
    for (int g = 0; g < 8; ++g) {
        s[g] += __shfl_xor(s[g], 16);
        s[g] += __shfl_xor(s[g], 32);
        q[g] += __shfl_xor(q[g], 16);
        q[g] += __shfl_xor(q[g], 32);
    }

    __shared__ float redS[4][OUT_CH];
    __shared__ float redQ[4][OUT_CH];
    if (quad == 0) {
#pragma unroll
        for (int g = 0; g < 8; ++g) {
            redS[w][g * 16 + col] = s[g];
            redQ[w][g * 16 + col] = q[g];
        }
    }
    __syncthreads();
    if (threadIdx.x < OUT_CH) {
        int c = threadIdx.x;
        float a = redS[0][c] + redS[1][c] + redS[2][c] + redS[3][c];
        float b = redQ[0][c] + redQ[1][c] + redQ[2][c] + redQ[3][c];
        atomicAdd(&sums[c], a);
        atomicAdd(&sums[OUT_CH + c], b);
    }
}

// y = gamma*(x-mean)*rsqrt(var+eps)+beta, relu; in-place, float4.
__global__ void __launch_bounds__(256) bn_relu_kernel(
    float4* __restrict__ out,
    const float* __restrict__ sums,
    const float* __restrict__ gamma,
    const float* __restrict__ beta,
    int total4, float inv_n)
{
    int idx = blockIdx.x * 256 + threadIdx.x;
    if (idx >= total4) return;
    int c0 = (idx & 31) * 4;
    float4 v = out[idx];
    float r[4] = {v.x, v.y, v.z, v.w};
#pragma unroll
    for (int j = 0; j < 4; ++j) {
        int c = c0 + j;
        float mean = sums[c] * inv_n;
        float var = sums[OUT_CH + c] * inv_n - mean * mean;
        float scale = gamma[c] * rsqrtf(var + 1e-5f);
        float y = (r[j] - mean) * scale + beta[c];
        r[j] = fmaxf(y, 0.0f);
    }
    out[idx] = make_float4(r[0], r[1], r[2], r[3]);
}

// ---------- fallback (atomic scatter) if ws too small ----------

__global__ void __launch_bounds__(256) zero_kernel(float4* __restrict__ out, int n4,
                                                   float* __restrict__ sums) {
    int idx = blockIdx.x * 256 + threadIdx.x;
    if (idx < n4) out[idx] = make_float4(0.f, 0.f, 0.f, 0.f);
    if (blockIdx.x == 0 && threadIdx.x < 2 * OUT_CH) sums[threadIdx.x] = 0.f;
}

__global__ void __launch_bounds__(256) scatter_gemm_kernel(
    const float* __restrict__ feats,
    const float* __restrict__ W,
    const int* __restrict__ in_idx,
    const int* __restrict__ out_idx,
    const int* __restrict__ mask,
    float* __restrict__ acc,
    int R)
{
    const int lane = threadIdx.x & 63;
    const int waveId = threadIdx.x >> 6;
    const int half = waveId & 1;
    const int pair = waveId >> 1;
    const int k = blockIdx.y;
    const int c = half * 64 + lane;

    float wreg[IN_CH];
    const float* __restrict__ wp = W + (size_t)k * IN_CH * OUT_CH + c;
#pragma unroll
    for (int i = 0; i < IN_CH; ++i) wreg[i] = wp[i * OUT_CH];

    const int r0 = blockIdx.x * 128;
    const int rEnd = min(r0 + 128, R);
    const int* __restrict__ maskK = mask + (size_t)k * R;
    const int* __restrict__ inK = in_idx + (size_t)k * R;
    const int* __restrict__ outK = out_idx + (size_t)k * R;

    for (int r = r0 + pair; r < rEnd; r += 2) {
        if (!__builtin_amdgcn_readfirstlane(maskK[r])) continue;
        int in = __builtin_amdgcn_readfirstlane(inK[r]);
        int out = __builtin_amdgcn_readfirstlane(outK[r]);
        const float* __restrict__ f = feats + (size_t)in * IN_CH;
        float s = 0.f, s1 = 0.f;
#pragma unroll
        for (int i = 0; i < IN_CH; i += 2) {
            s = fmaf(wreg[i], f[i], s);
            s1 = fmaf(wreg[i + 1], f[i + 1], s1);
        }
        atomicAdd(acc + (size_t)out * OUT_CH + c, s + s1);
    }
}

__global__ void __launch_bounds__(128) stats_kernel(
    const float* __restrict__ acc,
    float* __restrict__ sums,
    int n_out)
{
    int c = threadIdx.x;
    float s = 0.0f, s2 = 0.0f;
    for (int r = blockIdx.x; r < n_out; r += gridDim.x) {
        float v = acc[(size_t)r * OUT_CH + c];
        s += v;
        s2 += v * v;
    }
    atomicAdd(&sums[c], s);
    atomicAdd(&sums[OUT_CH + c], s2);
}

// ---------- launch ----------

extern "C" void kernel_launch(void* const* d_in, const int* in_sizes, int n_in,
                              void* d_out, int out_size, void* d_ws, size_t ws_size,
                              hipStream_t stream) {
    const float* feats   = (const float*)d_in[0];
    const float* W       = (const float*)d_in[1];
    const float* gamma   = (const float*)d_in[2];
    const float* beta    = (const float*)d_in[3];
    const int*   in_idx  = (const int*)d_in[4];
    const int*   out_idx = (const int*)d_in[5];
    const int*   mask    = (const int*)d_in[6];   // bool stored as int32

    const int R = in_sizes[4] / 9;
    const int n_out = out_size / OUT_CH;
    const int N_in = in_sizes[0] / IN_CH;
    float* acc = (float*)d_out;

    size_t off_inv  = 0;
    size_t sz_inv   = (size_t)n_out * 9 * sizeof(int);
    size_t off_sums = (off_inv + sz_inv + 15) & ~(size_t)15;
    size_t off_fb   = (off_sums + 1024 + 15) & ~(size_t)15;
    size_t off_wbt  = (off_fb + (size_t)(N_in + 1) * IN_CH * 2 + 15) & ~(size_t)15;
    size_t needed   = off_wbt + (size_t)9 * OUT_CH * IN_CH * 2;

    if (ws_size >= needed) {
        int*    inv  = (int*)((char*)d_ws + off_inv);
        float*  sums = (float*)((char*)d_ws + off_sums);
        ushort* fb   = (ushort*)((char*)d_ws + off_fb);
        ushort* wbt  = (ushort*)((char*)d_ws + off_wbt);

        int invTot = n_out * 9;
        init_inv_kernel<<<(invTot + 255) / 256, 256, 0, stream>>>(
            inv, invTot, N_in, sums);

        int n4 = N_in * IN_CH / 4;
        feats_bf16_kernel<<<(n4 + 16 + 255) / 256, 256, 0, stream>>>(
            (const float4*)feats, fb, n4);

        wbt_kernel<<<(9 * OUT_CH * IN_CH + 255) / 256, 256, 0, stream>>>(W, wbt);

        dim3 gridB((R + 255) / 256, 9);
        build_inv_kernel<<<gridB, 256, 0, stream>>>(in_idx, out_idx, mask, inv, R);

        fused_out_kernel<<<(n_out + 127) / 128, 256, 0, stream>>>(
            fb, wbt, inv, acc, sums, n_out, N_in);

        int total4 = out_size / 4;
        bn_relu_kernel<<<(total4 + 255) / 256, 256, 0, stream>>>(
            (float4*)acc, sums, gamma, beta, total4, 1.0f / (float)n_out);
    } else {
        float* sums = (float*)d_ws;
        int n4 = out_size / 4;
        zero_kernel<<<(n4 + 255) / 256, 256, 0, stream>>>((float4*)acc, n4, sums);

        dim3 grid((R + 127) / 128, 9);
        scatter_gemm_kernel<<<grid, 256, 0, stream>>>(feats, W, in_idx, out_idx, mask, acc, R);

        stats_kernel<<<2048, 128, 0, stream>>>(acc, sums, n_out);

        int total4 = out_size / 4;
        bn_relu_kernel<<<(total4 + 255) / 256, 256, 0, stream>>>(
            (float4*)acc, sums, gamma, beta, total4, 1.0f / (float)n_out);
    }
}